// Round 6
// baseline (1694.993 us; speedup 1.0000x reference)
//
#include <hip/hip_runtime.h>
#include <stdint.h>

#define T_STEPS 256
#define EMBD 10
#define MB 16          // batch rows per block
#define NBLK 64        // 1024 / MB
#define NKIT 9         // K = 288 = 9 * 32 (256 h + 10 x + 1 bias + pad)

typedef __attribute__((ext_vector_type(8))) short bf16x8;
typedef __attribute__((ext_vector_type(4))) float f32x4;

// Opaque pin: the asm "writes" each 32-bit component, so LLVM cannot
// rematerialize the load inside the t-loop -- the frag must stay live in
// VGPRs. (R2/R3/R4 silently re-streamed B from L2 every step; VGPR_Count
// 108/128 proved it. R5's 128-bit "+v" tie failed to compile -- the backend
// only supports tied constraints on 32-bit regs, so pin per component.)
#define PIN4(v) asm volatile("" : "+v"((v).x), "+v"((v).y), "+v"((v).z), "+v"((v).w))

__device__ __forceinline__ unsigned short f2bf(float f) {
    union { float f; unsigned int u; } v; v.f = f;
    unsigned int u = v.u;
    unsigned int r = (u + 0x7FFFu + ((u >> 16) & 1u)) >> 16;  // RNE
    return (unsigned short)r;
}
__device__ __forceinline__ float sig_fast(float x) {
    return __frcp_rn(1.0f + exp2f(-1.4426950408889634f * x));
}
__device__ __forceinline__ float tanh_fast(float x) {
    return 1.0f - 2.0f * __frcp_rn(exp2f(2.8853900817779268f * x) + 1.0f);
}

// 4 MFMAs (one per gate) sharing one A-frag.
__device__ __forceinline__ void kit4(f32x4 acc[4], int4 a, const int4* b) {
#pragma unroll
    for (int g = 0; g < 4; g++)
        acc[g] = __builtin_amdgcn_mfma_f32_16x16x32_bf16(
            __builtin_bit_cast(bf16x8, a),
            __builtin_bit_cast(bf16x8, b[g]), acc[g], 0, 0, 0);
}

// ---------------------------------------------------------------------------
// K1: swizzled bf16 weights Wfull[288][1024] in MFMA B-frag order.
// Layout: [kit 0..8][ntile 0..63][lane 0..63] x 16B.
// Lane's 8 bf16: Wfull[k = kit*32 + (lane>>4)*8 + j][n = ntile*16 + (lane&15)]
// k<256 -> Wh[k][:], 256..265 -> Wx[k-256][:], 266 -> bias, else 0.
// ---------------------------------------------------------------------------
__global__ __launch_bounds__(64) void build_wswz(
    const float* __restrict__ Wgx, const float* __restrict__ Wgh, const float* __restrict__ bg,
    const float* __restrict__ Wix, const float* __restrict__ Wih, const float* __restrict__ bi,
    const float* __restrict__ Wfx, const float* __restrict__ Wfh, const float* __restrict__ bf_,
    const float* __restrict__ Wox, const float* __restrict__ Woh, const float* __restrict__ bo,
    unsigned short* __restrict__ wswz)
{
    int g   = blockIdx.x / NKIT;   // ntile
    int kit = blockIdx.x % NKIT;
    int lane = threadIdx.x;
    int n = g * 16 + (lane & 15);
    int q = n >> 8;
    int col = n & 255;
    const float* Wh = (q == 0) ? Wgh : (q == 1) ? Wih : (q == 2) ? Wfh : Woh;
    const float* Wx = (q == 0) ? Wgx : (q == 1) ? Wix : (q == 2) ? Wfx : Wox;
    const float* bb = (q == 0) ? bg  : (q == 1) ? bi  : (q == 2) ? bf_ : bo;
    int k0 = kit * 32 + (lane >> 4) * 8;

    int4 out;
    unsigned short* p = (unsigned short*)&out;
#pragma unroll
    for (int j = 0; j < 8; j++) {
        int k = k0 + j;
        float v = 0.0f;
        if (k < 256)             v = Wh[k * 256 + col];
        else if (k < 256 + EMBD) v = Wx[(k - 256) * 256 + col];
        else if (k == 266)       v = bb[col];
        p[j] = f2bf(v);
    }
    ((int4*)wswz)[(kit * 64 + g) * 64 + lane] = out;
}

// ---------------------------------------------------------------------------
// K2: persistent LSTM. 64 blocks x 512 threads (8 waves, 2/SIMD, 256 reg cap).
// Per-CU B residency: kits 0-3 + kit 8 PINNED in VGPRs (160 regs, asm-pinned
// against remat), kits 5-6 in LDS (128 KB), kits 4 & 7 streamed from L2 each
// step (128 KB/step) through a 4-frag landing buffer. u-split (2 passes/step)
// keeps acc at 16 regs; total ~245 < 256.
// A-tile (16x288, A-frag order) double-buffered in LDS; ONE barrier/step.
// ---------------------------------------------------------------------------
__global__ __launch_bounds__(512, 2) void lstm_main(
    const int*   __restrict__ xtok,   // [1024][1][256]
    const float* __restrict__ emb,    // [32000][10]
    const float* __restrict__ Wph,    // [256][10]
    const float* __restrict__ bp,     // [10]
    const unsigned short* __restrict__ wswz,
    float* __restrict__ out)          // [1024][10]
{
    __shared__ __align__(16) unsigned short A_lds[2][8 * 64 * 8];   // 16 KB (kits 0-7)
    __shared__ __align__(16) unsigned short A8_lds[2][64 * 8];      // 2 KB (kit 8)
    __shared__ __align__(16) int4 B_lds[2 * 64 * 64];               // 128 KB (kits 5,6)
    __shared__ float outacc[MB * 10];

    const int tid  = threadIdx.x;
    const int w    = tid >> 6;        // wave 0..7
    const int lane = tid & 63;
    const int quad = lane >> 4;
    const int l15  = lane & 15;
    const int blk  = blockIdx.x;

    const int m_x = tid >> 4;         // x-gather: batch row 0..15 (tid<256)
    const int e_x = tid & 15;         // emb element (valid if <10)

    const int4* Bg = (const int4*)wswz;

    // --- prologue: LDS B-cache (kits 5,6) ---
    for (int i = tid; i < 2 * 64 * 64; i += 512)
        B_lds[i] = Bg[5 * 4096 + i];

    // --- register-resident B: kits 0-3 and kit 8, indexed [u][kit][gate] ---
    int4 breg[2][4][4];
#pragma unroll
    for (int u = 0; u < 2; u++)
#pragma unroll
        for (int kit = 0; kit < 4; kit++)
#pragma unroll
            for (int g = 0; g < 4; g++)
                breg[u][kit][g] = Bg[(kit * 64 + g * 16 + 2 * w + u) * 64 + lane];
    int4 b8[2][4];
#pragma unroll
    for (int u = 0; u < 2; u++)
#pragma unroll
        for (int g = 0; g < 4; g++)
            b8[u][g] = Bg[(8 * 64 + g * 16 + 2 * w + u) * 64 + lane];

    // pin everything so LLVM cannot sink/remat the loads into the t-loop
#pragma unroll
    for (int u = 0; u < 2; u++) {
#pragma unroll
        for (int kit = 0; kit < 4; kit++)
#pragma unroll
            for (int g = 0; g < 4; g++) PIN4(breg[u][kit][g]);
#pragma unroll
        for (int g = 0; g < 4; g++) PIN4(b8[u][g]);
    }

    // --- init A double buffer: zeros, bias row (both), x_0 (buf 0) ---
    {
        int4 z4 = {0, 0, 0, 0};
        for (int i = tid; i < 1024; i += 512) ((int4*)A_lds)[i] = z4;
        if (tid < 128) ((int4*)A8_lds)[tid] = z4;
    }
    __syncthreads();
    if (tid < 16) {
        // kit8 local k=10 (bias=1.0): lp = m+16, elem 2
        A8_lds[0][(16 + tid) * 8 + 2] = 0x3F80;
        A8_lds[1][(16 + tid) * 8 + 2] = 0x3F80;
    }
    if (tid < 256 && e_x < EMBD) {
        int tok = xtok[(blk * MB + m_x) * T_STEPS + 0];
        float v = emb[tok * EMBD + e_x];
        A8_lds[0][(m_x + 16 * (e_x >> 3)) * 8 + (e_x & 7)] = f2bf(v);
    }
    __syncthreads();

    float c[2][4], hreg[2][4];
#pragma unroll
    for (int u = 0; u < 2; u++)
#pragma unroll
        for (int r = 0; r < 4; r++) { c[u][r] = 0.0f; hreg[u][r] = 0.0f; }

    for (int t = 0; t < T_STEPS; t++) {
        const int4* Ab  = (const int4*)A_lds[t & 1];
        const int4* A8b = (const int4*)A8_lds[t & 1];
        unsigned short* Aw  = A_lds[(t + 1) & 1];
        unsigned short* A8w = A8_lds[(t + 1) & 1];

        // x(t+1) prefetch (independent; overlaps MFMA)
        float xval = 0.0f;
        const bool do_x = (t < T_STEPS - 1) && (tid < 256) && (e_x < EMBD);
        if ((t < T_STEPS - 1) && (tid < 256)) {
            int tok = xtok[(blk * MB + m_x) * T_STEPS + (t + 1)];
            if (e_x < EMBD) xval = emb[tok * EMBD + e_x];
        }

#pragma unroll
        for (int u = 0; u < 2; u++) {
            // issue streamed kit 4 early (used 5 phases later)
            int4 land[4];
#pragma unroll
            for (int g = 0; g < 4; g++)
                land[g] = Bg[(4 * 64 + g * 16 + 2 * w + u) * 64 + lane];

            // A window (3 deep) over kit order 0,1,2,3,5,4,6,8,7
            int4 w0 = Ab[0 * 64 + lane];
            int4 w1 = Ab[1 * 64 + lane];
            int4 w2 = Ab[2 * 64 + lane];

            f32x4 acc[4];
#pragma unroll
            for (int g = 0; g < 4; g++) acc[g] = (f32x4){0.f, 0.f, 0.f, 0.f};

            kit4(acc, w0, breg[u][0]); w0 = Ab[3 * 64 + lane];
            kit4(acc, w1, breg[u][1]); w1 = Ab[5 * 64 + lane];
            kit4(acc, w2, breg[u][2]); w2 = Ab[4 * 64 + lane];
            kit4(acc, w0, breg[u][3]); w0 = Ab[6 * 64 + lane];
            // kit 5 (LDS)
            {
                int4 bt[4];
#pragma unroll
                for (int g = 0; g < 4; g++)
                    bt[g] = B_lds[(g * 16 + 2 * w + u) * 64 + lane];
                kit4(acc, w1, bt);
            }
            w1 = A8b[lane];
            // kit 4 (streamed), then reissue landing regs with kit 7
            kit4(acc, w2, land);
            w2 = Ab[7 * 64 + lane];
#pragma unroll
            for (int g = 0; g < 4; g++)
                land[g] = Bg[(7 * 64 + g * 16 + 2 * w + u) * 64 + lane];
            // kit 6 (LDS)
            {
                int4 bt[4];
#pragma unroll
                for (int g = 0; g < 4; g++)
                    bt[g] = B_lds[4096 + (g * 16 + 2 * w + u) * 64 + lane];
                kit4(acc, w0, bt);
            }
            // kit 8 (x + bias, resident)
            kit4(acc, w1, b8[u]);
            // kit 7 (streamed)
            kit4(acc, w2, land);

            // gate math: z[m][n], m = quad*4+r, n = gate*256 + 32w + 16u + l15
#pragma unroll
            for (int r = 0; r < 4; r++) {
                float gg = tanh_fast(acc[0][r]);
                float ii = sig_fast(acc[1][r]);
                float ff = sig_fast(acc[2][r]);
                float oo = sig_fast(acc[3][r]);
                float cn = gg * ii + c[u][r] * ff;
                c[u][r] = cn;
                float hh = tanh_fast(cn) * oo;
                hreg[u][r] = hh;
                int m = quad * 4 + r;
                int hcol = 32 * w + 16 * u + l15;
                int lp = m + 16 * ((hcol >> 3) & 3);
                Aw[(w * 64 + lp) * 8 + (hcol & 7)] = f2bf(hh);
            }
        }
        if (t == T_STEPS - 1) break;
        if (do_x)
            A8w[(m_x + 16 * (e_x >> 3)) * 8 + (e_x & 7)] = f2bf(xval);
        __syncthreads();  // single barrier: A(t+1) complete
    }

    // --- epilogue: out[m][cls] = sum_hcol h[m][hcol]*Wph[hcol][cls] + bp ---
    float part[4][10];
#pragma unroll
    for (int r = 0; r < 4; r++)
#pragma unroll
        for (int cl = 0; cl < 10; cl++) part[r][cl] = 0.0f;
#pragma unroll
    for (int u = 0; u < 2; u++) {
        int hcol = 32 * w + 16 * u + l15;
#pragma unroll
        for (int cl = 0; cl < 10; cl++) {
            float wv = Wph[hcol * 10 + cl];
#pragma unroll
            for (int r = 0; r < 4; r++) part[r][cl] += hreg[u][r] * wv;
        }
    }
#pragma unroll
    for (int off = 1; off < 16; off <<= 1)
#pragma unroll
        for (int r = 0; r < 4; r++)
#pragma unroll
            for (int cl = 0; cl < 10; cl++)
                part[r][cl] += __shfl_xor(part[r][cl], off, 64);

    if (tid < MB * 10) outacc[tid] = 0.0f;
    __syncthreads();
    if (l15 == 0) {
#pragma unroll
        for (int r = 0; r < 4; r++) {
            int m = quad * 4 + r;
#pragma unroll
            for (int cl = 0; cl < 10; cl++)
                atomicAdd(&outacc[m * 10 + cl], part[r][cl]);
        }
    }
    __syncthreads();
    if (tid < MB * 10) {
        int m = tid / 10, cl = tid - m * 10;
        out[(blk * MB + m) * 10 + cl] = outacc[tid] + bp[cl];
    }
}

extern "C" void kernel_launch(void* const* d_in, const int* in_sizes, int n_in,
                              void* d_out, int out_size, void* d_ws, size_t ws_size,
                              hipStream_t stream) {
    const int*   x    = (const int*)  d_in[0];
    const float* emb  = (const float*)d_in[1];
    const float* Wgx  = (const float*)d_in[2];
    const float* Wgh  = (const float*)d_in[3];
    const float* bg   = (const float*)d_in[4];
    const float* Wix  = (const float*)d_in[5];
    const float* Wih  = (const float*)d_in[6];
    const float* bi   = (const float*)d_in[7];
    const float* Wfx  = (const float*)d_in[8];
    const float* Wfh  = (const float*)d_in[9];
    const float* bf_  = (const float*)d_in[10];
    const float* Wox  = (const float*)d_in[11];
    const float* Woh  = (const float*)d_in[12];
    const float* bo   = (const float*)d_in[13];
    const float* Wph  = (const float*)d_in[14];
    const float* bp   = (const float*)d_in[15];

    unsigned short* wswz = (unsigned short*)d_ws;  // 9*64*64*16 = 576 KB

    build_wswz<<<NBLK * NKIT, 64, 0, stream>>>(Wgx, Wgh, bg, Wix, Wih, bi,
                                               Wfx, Wfh, bf_, Wox, Woh, bo, wswz);
    lstm_main<<<NBLK, 512, 0, stream>>>(x, emb, Wph, bp, wswz, (float*)d_out);
}

// Round 8
// 1643.666 us; speedup vs baseline: 1.0312x; 1.0312x over previous
//
#include <hip/hip_runtime.h>
#include <stdint.h>

#define T_STEPS 256
#define EMBD 10
#define MB 16          // batch rows per block
#define NBLK 64        // 1024 / MB
#define NKIT 9         // K = 288 = 9 * 32 (256 h + 10 x + 1 bias + pad)

typedef __attribute__((ext_vector_type(8))) short bf16x8;
typedef __attribute__((ext_vector_type(4))) float f32x4;

__device__ __forceinline__ unsigned short f2bf(float f) {
    union { float f; unsigned int u; } v; v.f = f;
    unsigned int u = v.u;
    unsigned int r = (u + 0x7FFFu + ((u >> 16) & 1u)) >> 16;  // RNE
    return (unsigned short)r;
}
__device__ __forceinline__ float sig_fast(float x) {
    return __frcp_rn(1.0f + exp2f(-1.4426950408889634f * x));
}
__device__ __forceinline__ float tanh_fast(float x) {
    return 1.0f - 2.0f * __frcp_rn(exp2f(2.8853900817779268f * x) + 1.0f);
}

// 4 MFMAs (one per gate) sharing one A-frag.
__device__ __forceinline__ void kit4(f32x4 acc[4], int4 a, const int4* b) {
#pragma unroll
    for (int g = 0; g < 4; g++)
        acc[g] = __builtin_amdgcn_mfma_f32_16x16x32_bf16(
            __builtin_bit_cast(bf16x8, a),
            __builtin_bit_cast(bf16x8, b[g]), acc[g], 0, 0, 0);
}

// ---------------------------------------------------------------------------
// K1: swizzled bf16 weights Wfull[288][1024] in MFMA B-frag order.
// Layout: [kit 0..8][ntile 0..63][lane 0..63] x 16B.
// Lane's 8 bf16: Wfull[k = kit*32 + (lane>>4)*8 + j][n = ntile*16 + (lane&15)]
// k<256 -> Wh[k][:], 256..265 -> Wx[k-256][:], 266 -> bias, else 0.
// ---------------------------------------------------------------------------
__global__ __launch_bounds__(64) void build_wswz(
    const float* __restrict__ Wgx, const float* __restrict__ Wgh, const float* __restrict__ bg,
    const float* __restrict__ Wix, const float* __restrict__ Wih, const float* __restrict__ bi,
    const float* __restrict__ Wfx, const float* __restrict__ Wfh, const float* __restrict__ bf_,
    const float* __restrict__ Wox, const float* __restrict__ Woh, const float* __restrict__ bo,
    unsigned short* __restrict__ wswz)
{
    int g   = blockIdx.x / NKIT;   // ntile
    int kit = blockIdx.x % NKIT;
    int lane = threadIdx.x;
    int n = g * 16 + (lane & 15);
    int q = n >> 8;
    int col = n & 255;
    const float* Wh = (q == 0) ? Wgh : (q == 1) ? Wih : (q == 2) ? Wfh : Woh;
    const float* Wx = (q == 0) ? Wgx : (q == 1) ? Wix : (q == 2) ? Wfx : Wox;
    const float* bb = (q == 0) ? bg  : (q == 1) ? bi  : (q == 2) ? bf_ : bo;
    int k0 = kit * 32 + (lane >> 4) * 8;

    int4 out;
    unsigned short* p = (unsigned short*)&out;
#pragma unroll
    for (int j = 0; j < 8; j++) {
        int k = k0 + j;
        float v = 0.0f;
        if (k < 256)             v = Wh[k * 256 + col];
        else if (k < 256 + EMBD) v = Wx[(k - 256) * 256 + col];
        else if (k == 266)       v = bb[col];
        p[j] = f2bf(v);
    }
    ((int4*)wswz)[(kit * 64 + g) * 64 + lane] = out;
}

// ---------------------------------------------------------------------------
// K2: persistent LSTM. 64 blocks x 512 threads. Grid is 1 block/CU, so
// exactly 2 waves/SIMD run regardless of register count -- waves_per_eu(2,2)
// pins the allocator's occupancy target to 2 so it will actually USE the
// 256-reg budget instead of capping at 128 and re-streaming B every step
// (R4/R6: VGPR_Count=128, 448 KB/step streamed at the ~29 B/cyc L2 ceiling).
// Residency plan: kits 0-3 + kit 8 in VGPRs (160 regs), kits 5-6 in LDS
// (128 KB), kits 4 & 7 streamed per step (128 KB/step). u-split keeps acc
// at 16 regs; total demand ~245 < 256.
// ---------------------------------------------------------------------------
__global__ __launch_bounds__(512)
__attribute__((amdgpu_waves_per_eu(2, 2)))
void lstm_main(
    const int*   __restrict__ xtok,   // [1024][1][256]
    const float* __restrict__ emb,    // [32000][10]
    const float* __restrict__ Wph,    // [256][10]
    const float* __restrict__ bp,     // [10]
    const unsigned short* __restrict__ wswz,
    float* __restrict__ out)          // [1024][10]
{
    __shared__ __align__(16) unsigned short A_lds[2][8 * 64 * 8];   // 16 KB (kits 0-7)
    __shared__ __align__(16) unsigned short A8_lds[2][64 * 8];      // 2 KB (kit 8)
    __shared__ __align__(16) int4 B_lds[2 * 64 * 64];               // 128 KB (kits 5,6)
    __shared__ float outacc[MB * 10];

    const int tid  = threadIdx.x;
    const int w    = tid >> 6;        // wave 0..7
    const int lane = tid & 63;
    const int quad = lane >> 4;
    const int l15  = lane & 15;
    const int blk  = blockIdx.x;

    const int m_x = tid >> 4;         // x-gather: batch row 0..15 (tid<256)
    const int e_x = tid & 15;         // emb element (valid if <10)

    const int4* Bg = (const int4*)wswz;

    // --- prologue: LDS B-cache (kits 5,6) ---
    for (int i = tid; i < 2 * 64 * 64; i += 512)
        B_lds[i] = Bg[5 * 4096 + i];

    // --- register-resident B: kits 0-3 and kit 8, indexed [u][kit][gate] ---
    int4 breg[2][4][4];
#pragma unroll
    for (int u = 0; u < 2; u++)
#pragma unroll
        for (int kit = 0; kit < 4; kit++)
#pragma unroll
            for (int g = 0; g < 4; g++)
                breg[u][kit][g] = Bg[(kit * 64 + g * 16 + 2 * w + u) * 64 + lane];
    int4 b8[2][4];
#pragma unroll
    for (int u = 0; u < 2; u++)
#pragma unroll
        for (int g = 0; g < 4; g++)
            b8[u][g] = Bg[(8 * 64 + g * 16 + 2 * w + u) * 64 + lane];

    // --- init A double buffer: zeros, bias row (both), x_0 (buf 0) ---
    {
        int4 z4 = {0, 0, 0, 0};
        for (int i = tid; i < 1024; i += 512) ((int4*)A_lds)[i] = z4;
        if (tid < 128) ((int4*)A8_lds)[tid] = z4;
    }
    __syncthreads();
    if (tid < 16) {
        // kit8 local k=10 (bias=1.0): lp = m+16, elem 2
        A8_lds[0][(16 + tid) * 8 + 2] = 0x3F80;
        A8_lds[1][(16 + tid) * 8 + 2] = 0x3F80;
    }
    if (tid < 256 && e_x < EMBD) {
        int tok = xtok[(blk * MB + m_x) * T_STEPS + 0];
        float v = emb[tok * EMBD + e_x];
        A8_lds[0][(m_x + 16 * (e_x >> 3)) * 8 + (e_x & 7)] = f2bf(v);
    }
    __syncthreads();

    float c[2][4], hreg[2][4];
#pragma unroll
    for (int u = 0; u < 2; u++)
#pragma unroll
        for (int r = 0; r < 4; r++) { c[u][r] = 0.0f; hreg[u][r] = 0.0f; }

    for (int t = 0; t < T_STEPS; t++) {
        const int4* Ab  = (const int4*)A_lds[t & 1];
        const int4* A8b = (const int4*)A8_lds[t & 1];
        unsigned short* Aw  = A_lds[(t + 1) & 1];
        unsigned short* A8w = A8_lds[(t + 1) & 1];

        // x(t+1) prefetch (independent; overlaps MFMA)
        float xval = 0.0f;
        const bool do_x = (t < T_STEPS - 1) && (tid < 256) && (e_x < EMBD);
        if ((t < T_STEPS - 1) && (tid < 256)) {
            int tok = xtok[(blk * MB + m_x) * T_STEPS + (t + 1)];
            if (e_x < EMBD) xval = emb[tok * EMBD + e_x];
        }

#pragma unroll
        for (int u = 0; u < 2; u++) {
            // issue streamed kit 4 early (used 5 phases later)
            int4 land[4];
#pragma unroll
            for (int g = 0; g < 4; g++)
                land[g] = Bg[(4 * 64 + g * 16 + 2 * w + u) * 64 + lane];

            // A window (3 deep) over kit order 0,1,2,3,5,4,6,8,7
            int4 w0 = Ab[0 * 64 + lane];
            int4 w1 = Ab[1 * 64 + lane];
            int4 w2 = Ab[2 * 64 + lane];

            f32x4 acc[4];
#pragma unroll
            for (int g = 0; g < 4; g++) acc[g] = (f32x4){0.f, 0.f, 0.f, 0.f};

            kit4(acc, w0, breg[u][0]); w0 = Ab[3 * 64 + lane];
            kit4(acc, w1, breg[u][1]); w1 = Ab[5 * 64 + lane];
            kit4(acc, w2, breg[u][2]); w2 = Ab[4 * 64 + lane];
            kit4(acc, w0, breg[u][3]); w0 = Ab[6 * 64 + lane];
            // kit 5 (LDS)
            {
                int4 bt[4];
#pragma unroll
                for (int g = 0; g < 4; g++)
                    bt[g] = B_lds[(g * 16 + 2 * w + u) * 64 + lane];
                kit4(acc, w1, bt);
            }
            w1 = A8b[lane];
            // kit 4 (streamed), then reissue landing regs with kit 7
            kit4(acc, w2, land);
            w2 = Ab[7 * 64 + lane];
#pragma unroll
            for (int g = 0; g < 4; g++)
                land[g] = Bg[(7 * 64 + g * 16 + 2 * w + u) * 64 + lane];
            // kit 6 (LDS)
            {
                int4 bt[4];
#pragma unroll
                for (int g = 0; g < 4; g++)
                    bt[g] = B_lds[4096 + (g * 16 + 2 * w + u) * 64 + lane];
                kit4(acc, w0, bt);
            }
            // kit 8 (x + bias, resident)
            kit4(acc, w1, b8[u]);
            // kit 7 (streamed)
            kit4(acc, w2, land);

            // gate math: z[m][n], m = quad*4+r, n = gate*256 + 32w + 16u + l15
#pragma unroll
            for (int r = 0; r < 4; r++) {
                float gg = tanh_fast(acc[0][r]);
                float ii = sig_fast(acc[1][r]);
                float ff = sig_fast(acc[2][r]);
                float oo = sig_fast(acc[3][r]);
                float cn = gg * ii + c[u][r] * ff;
                c[u][r] = cn;
                float hh = tanh_fast(cn) * oo;
                hreg[u][r] = hh;
                int m = quad * 4 + r;
                int hcol = 32 * w + 16 * u + l15;
                int lp = m + 16 * ((hcol >> 3) & 3);
                Aw[(w * 64 + lp) * 8 + (hcol & 7)] = f2bf(hh);
            }
        }
        if (t == T_STEPS - 1) break;
        if (do_x)
            A8w[(m_x + 16 * (e_x >> 3)) * 8 + (e_x & 7)] = f2bf(xval);
        __syncthreads();  // single barrier: A(t+1) complete
    }

    // --- epilogue: out[m][cls] = sum_hcol h[m][hcol]*Wph[hcol][cls] + bp ---
    float part[4][10];
#pragma unroll
    for (int r = 0; r < 4; r++)
#pragma unroll
        for (int cl = 0; cl < 10; cl++) part[r][cl] = 0.0f;
#pragma unroll
    for (int u = 0; u < 2; u++) {
        int hcol = 32 * w + 16 * u + l15;
#pragma unroll
        for (int cl = 0; cl < 10; cl++) {
            float wv = Wph[hcol * 10 + cl];
#pragma unroll
            for (int r = 0; r < 4; r++) part[r][cl] += hreg[u][r] * wv;
        }
    }
#pragma unroll
    for (int off = 1; off < 16; off <<= 1)
#pragma unroll
        for (int r = 0; r < 4; r++)
#pragma unroll
            for (int cl = 0; cl < 10; cl++)
                part[r][cl] += __shfl_xor(part[r][cl], off, 64);

    if (tid < MB * 10) outacc[tid] = 0.0f;
    __syncthreads();
    if (l15 == 0) {
#pragma unroll
        for (int r = 0; r < 4; r++) {
            int m = quad * 4 + r;
#pragma unroll
            for (int cl = 0; cl < 10; cl++)
                atomicAdd(&outacc[m * 10 + cl], part[r][cl]);
        }
    }
    __syncthreads();
    if (tid < MB * 10) {
        int m = tid / 10, cl = tid - m * 10;
        out[(blk * MB + m) * 10 + cl] = outacc[tid] + bp[cl];
    }
}

extern "C" void kernel_launch(void* const* d_in, const int* in_sizes, int n_in,
                              void* d_out, int out_size, void* d_ws, size_t ws_size,
                              hipStream_t stream) {
    const int*   x    = (const int*)  d_in[0];
    const float* emb  = (const float*)d_in[1];
    const float* Wgx  = (const float*)d_in[2];
    const float* Wgh  = (const float*)d_in[3];
    const float* bg   = (const float*)d_in[4];
    const float* Wix  = (const float*)d_in[5];
    const float* Wih  = (const float*)d_in[6];
    const float* bi   = (const float*)d_in[7];
    const float* Wfx  = (const float*)d_in[8];
    const float* Wfh  = (const float*)d_in[9];
    const float* bf_  = (const float*)d_in[10];
    const float* Wox  = (const float*)d_in[11];
    const float* Woh  = (const float*)d_in[12];
    const float* bo   = (const float*)d_in[13];
    const float* Wph  = (const float*)d_in[14];
    const float* bp   = (const float*)d_in[15];

    unsigned short* wswz = (unsigned short*)d_ws;  // 9*64*64*16 = 576 KB

    build_wswz<<<NBLK * NKIT, 64, 0, stream>>>(Wgx, Wgh, bg, Wix, Wih, bi,
                                               Wfx, Wfh, bf_, Wox, Woh, bo, wswz);
    lstm_main<<<NBLK, 512, 0, stream>>>(x, emb, Wph, bp, wswz, (float*)d_out);
}